// Round 8
// baseline (4662.480 us; speedup 1.0000x reference)
//
#include <hip/hip_runtime.h>

#define E_EDGES 131072
#define D_IN 128
#define D_HID 512
#define D_OUT 128
#define CAP 64          // bucket capacity (Poisson(16); P(count>56) ~ 7e-14; clamped)
#define HSP 40          // hslice row pitch in ushorts (80 B): bank-spreading, b128-safe

typedef __bf16 bf16x8 __attribute__((ext_vector_type(8)));
typedef float f32x4 __attribute__((ext_vector_type(4)));

// round-to-nearest-even f32 -> bf16 bits
__device__ __forceinline__ unsigned short f2bf(float f) {
    unsigned int u = __float_as_uint(f);
    unsigned int r = (u + 0x7FFFu + ((u >> 16) & 1u)) >> 16;
    return (unsigned short)r;
}

// zero 8 MB (2M ints) as int4; grid 2048 x 256
__global__ void zero16(int* __restrict__ p) {
    int i = blockIdx.x * blockDim.x + threadIdx.x;
    ((int4*)p)[i] = make_int4(0, 0, 0, 0);
}

// Single-pass bucket scatter (replaces hist+scan+fill).
// cur line-padded: counter for segment e at cur[e*16] (64B per counter).
__global__ void bucketfill_kernel(const int* __restrict__ seg, int* __restrict__ cur,
                                  int* __restrict__ bucket, int nnz) {
    int i = blockIdx.x * blockDim.x + threadIdx.x;
    if (i * 4 < nnz) {
        int4 s = ((const int4*)seg)[i];
        int p0 = atomicAdd(&cur[s.x * 16], 1);
        int p1 = atomicAdd(&cur[s.y * 16], 1);
        int p2 = atomicAdd(&cur[s.z * 16], 1);
        int p3 = atomicAdd(&cur[s.w * 16], 1);
        if (p0 < CAP) bucket[s.x * CAP + p0] = i * 4;
        if (p1 < CAP) bucket[s.y * CAP + p1] = i * 4 + 1;
        if (p2 < CAP) bucket[s.z * CAP + p2] = i * 4 + 2;
        if (p3 < CAP) bucket[s.w * CAP + p3] = i * 4 + 3;
    }
}

// PROBE variant: rep loop, masked always-in-bounds slot, dummy targets.
__global__ void probe_bucketfill(const int* __restrict__ seg, int* __restrict__ cur_d,
                                 int* __restrict__ bucket_d, int nnz, int reps) {
    int i = blockIdx.x * blockDim.x + threadIdx.x;
    if (i * 4 < nnz) {
        int4 s = ((const int4*)seg)[i];
#pragma unroll 1
        for (int rep = 0; rep < reps; ++rep) {
            int p0 = atomicAdd(&cur_d[s.x * 16], 1);
            int p1 = atomicAdd(&cur_d[s.y * 16], 1);
            int p2 = atomicAdd(&cur_d[s.z * 16], 1);
            int p3 = atomicAdd(&cur_d[s.w * 16], 1);
            bucket_d[s.x * CAP + (p0 & 31)] = i * 4;
            bucket_d[s.y * CAP + (p1 & 31)] = i * 4 + 1;
            bucket_d[s.z * CAP + (p2 & 31)] = i * 4 + 2;
            bucket_d[s.w * CAP + (p3 & 31)] = i * 4 + 3;
            asm volatile("" ::: "memory");
        }
    }
}

// W1 [128][512] fp32 -> w1b = bf16 W1^T [512][128]; W2 [512][128] -> w2b [128][512]
__global__ void convw_kernel(const float* __restrict__ W1, const float* __restrict__ W2,
                             unsigned short* __restrict__ w1b, unsigned short* __restrict__ w2b) {
    int i = blockIdx.x * blockDim.x + threadIdx.x;
    if (i < D_IN * D_HID) {
        int n = i >> 7, k = i & 127;                 // w1b[n][k]
        w1b[i] = f2bf(W1[(size_t)k * D_HID + n]);
    } else {
        int i2 = i - D_IN * D_HID;
        int n = i2 >> 9, k = i2 & 511;               // w2b[n][k]
        w2b[i2] = f2bf(W2[(size_t)k * D_OUT + n]);
    }
}

// Gather-mean from buckets. 4 waves/block, wave owns 16 edges.
__global__ __launch_bounds__(256) void gather_kernel(
    const float* __restrict__ x, const int* __restrict__ bucket,
    const int* __restrict__ cur, unsigned short* __restrict__ meanb, int reps)
{
    const int tid  = threadIdx.x;
    const int lane = tid & 63;
    const int w    = tid >> 6;
    const int tile = blockIdx.x;      // 0..2047
    const int e0   = tile * 64 + w * 16;

    const int c  = lane & 31;         // float4 column (cols 4c..4c+3)
    const int rr = lane >> 5;         // slot parity within pair
    const char* xb = (const char*)x + c * 16;

    int nval = min(cur[(e0 + (lane & 15)) * 16], CAP);

#pragma unroll 1
    for (int rep = 0; rep < reps; ++rep) {
        for (int el = 0; el < 16; ++el) {
            const int n = __shfl(nval, el);
            const int* ce = bucket + (size_t)(e0 + el) * CAP;
            f32x4 a0 = {0.f, 0.f, 0.f, 0.f};
            f32x4 a1 = a0, a2 = a0, a3 = a0, a4 = a0, a5 = a0, a6 = a0, a7 = a0;
            for (int j = 0; j < n; j += 16) {
#define GSLOT(k, acc)                                                        \
                {                                                            \
                    const int jj = j + 2 * (k) + rr;                         \
                    if (jj < n) {                                            \
                        const int idx = ce[jj];                              \
                        f32x4 v = __builtin_nontemporal_load(                \
                            (const f32x4*)(xb + (size_t)idx * 512));         \
                        acc += v;                                            \
                    }                                                        \
                }
                GSLOT(0, a0) GSLOT(1, a1) GSLOT(2, a2) GSLOT(3, a3)
                GSLOT(4, a4) GSLOT(5, a5) GSLOT(6, a6) GSLOT(7, a7)
#undef GSLOT
            }
            f32x4 tot = ((a0 + a1) + (a2 + a3)) + ((a4 + a5) + (a6 + a7));
            tot[0] += __shfl_xor(tot[0], 32);
            tot[1] += __shfl_xor(tot[1], 32);
            tot[2] += __shfl_xor(tot[2], 32);
            tot[3] += __shfl_xor(tot[3], 32);
            const float scale = 1.0f / (float)(n > 0 ? n : 1);
            if (lane < 32) {
                unsigned int d0 = (unsigned)f2bf(tot[0] * scale) | ((unsigned)f2bf(tot[1] * scale) << 16);
                unsigned int d1 = (unsigned)f2bf(tot[2] * scale) | ((unsigned)f2bf(tot[3] * scale) << 16);
                *(uint2*)((char*)meanb + (size_t)(e0 + el) * 256 + c * 8) = make_uint2(d0, d1);
            }
        }
    }
}

// Pipelined fused MLP GEMM with BATCHED B-fragment loads.
// Block = 4 waves x 32 rows = 128 rows; grid 1024.
// Per ntp: issue all B1(ntp+1) + B2(ntp) loads -> ds_read a2(ntp) -> GEMM1(ntp+1)
// MFMA cluster + hslice write -> GEMM2(ntp) MFMA cluster.
__global__ __launch_bounds__(256) void gemm_kernel(
    const unsigned short* __restrict__ meanb, const unsigned short* __restrict__ w1b,
    const unsigned short* __restrict__ w2b, const float* __restrict__ b1,
    const float* __restrict__ b2, float* __restrict__ out, int reps)
{
    __shared__ unsigned short hs_all[4][2][32 * HSP];   // 4 waves x 2 bufs x 2560B = 20 KB

    const int tid  = threadIdx.x;
    const int lane = tid & 63;
    const int w    = tid >> 6;
    const int tile = blockIdx.x;            // 0..1023
    const int rb   = tile * 128 + w * 32;   // wave's 32 rows

    const int lrow = lane & 15;
    const int lgrp = lane >> 4;

    // per-lane GEMM2 bias (col = nt2*16 + lrow), loaded once
    float bias2[8];
#pragma unroll
    for (int nt2 = 0; nt2 < 8; ++nt2) bias2[nt2] = b2[nt2 * 16 + lrow];

    // ---- helpers (all loads batched into named register arrays) ----
    auto ldB1 = [&](int ntp, bf16x8 (&b1r)[2][4], float (&bia)[2]) {
#pragma unroll
        for (int half = 0; half < 2; ++half) {
            const int nt = ntp * 2 + half;
            bia[half] = b1[nt * 16 + lrow];
#pragma unroll
            for (int kk = 0; kk < 4; ++kk)
                b1r[half][kk] = *(const bf16x8*)(w1b +
                    (size_t)(nt * 16 + lrow) * 128 + kk * 32 + lgrp * 8);
        }
    };
    auto ldB2 = [&](int ntp, bf16x8 (&b2r)[8]) {
#pragma unroll
        for (int nt2 = 0; nt2 < 8; ++nt2)
            b2r[nt2] = *(const bf16x8*)(w2b +
                (size_t)(nt2 * 16 + lrow) * 512 + ntp * 32 + lgrp * 8);
    };

#pragma unroll 1
    for (int rep = 0; rep < reps; ++rep) {
        bf16x8 afrag[2][4];
#pragma unroll
        for (int mt = 0; mt < 2; ++mt)
#pragma unroll
            for (int kk = 0; kk < 4; ++kk)
                afrag[mt][kk] = *(const bf16x8*)(meanb +
                    (size_t)(rb + mt * 16 + lrow) * 128 + kk * 32 + lgrp * 8);

        f32x4 acc2[2][8];
#pragma unroll
        for (int mt = 0; mt < 2; ++mt)
#pragma unroll
            for (int nt2 = 0; nt2 < 8; ++nt2) {
                f32x4 bv = {bias2[nt2], bias2[nt2], bias2[nt2], bias2[nt2]};
                acc2[mt][nt2] = bv;
            }

        // GEMM1 compute+write for slice ntp using pre-loaded fragments
        auto g1wr = [&](int ntp, bf16x8 (&b1r)[2][4], float (&bia)[2]) {
            unsigned short* hw = &hs_all[w][ntp & 1][0];
#pragma unroll
            for (int half = 0; half < 2; ++half) {
                f32x4 acc0 = {bia[half], bia[half], bia[half], bia[half]};
                f32x4 acc1 = acc0;
#pragma unroll
                for (int kk = 0; kk < 4; ++kk) {
                    acc0 = __builtin_amdgcn_mfma_f32_16x16x32_bf16(afrag[0][kk], b1r[half][kk], acc0, 0, 0, 0);
                    acc1 = __builtin_amdgcn_mfma_f32_16x16x32_bf16(afrag[1][kk], b1r[half][kk], acc1, 0, 0, 0);
                }
#pragma unroll
                for (int r = 0; r < 4; ++r) {
                    hw[(lgrp * 4 + r) * HSP + half * 16 + lrow]        = f2bf(fmaxf(acc0[r], 0.f));
                    hw[(16 + lgrp * 4 + r) * HSP + half * 16 + lrow]   = f2bf(fmaxf(acc1[r], 0.f));
                }
            }
        };

        // ---- prologue: slice 0 through GEMM1 ----
        {
            bf16x8 b1r[2][4]; float bia[2];
            ldB1(0, b1r, bia);
            g1wr(0, b1r, bia);
        }

        // ---- main: ntp = 0..14 ----
#pragma unroll 1
        for (int ntp = 0; ntp < 15; ++ntp) {
            bf16x8 nb1[2][4]; float nbia[2];
            ldB1(ntp + 1, nb1, nbia);          // batched: 8 loads + 2 bias
            bf16x8 b2r[8];
            ldB2(ntp, b2r);                    // batched: 8 loads
            const unsigned short* hr = &hs_all[w][ntp & 1][0];
            const bf16x8 a20 = *(const bf16x8*)(hr + lrow * HSP + lgrp * 8);
            const bf16x8 a21 = *(const bf16x8*)(hr + (16 + lrow) * HSP + lgrp * 8);
            g1wr(ntp + 1, nb1, nbia);          // 16 MFMA + LDS writes
#pragma unroll
            for (int nt2 = 0; nt2 < 8; ++nt2) {  // 16 MFMA, B pre-loaded
                acc2[0][nt2] = __builtin_amdgcn_mfma_f32_16x16x32_bf16(a20, b2r[nt2], acc2[0][nt2], 0, 0, 0);
                acc2[1][nt2] = __builtin_amdgcn_mfma_f32_16x16x32_bf16(a21, b2r[nt2], acc2[1][nt2], 0, 0, 0);
            }
        }

        // ---- epilogue: slice 15 GEMM2 ----
        {
            bf16x8 b2r[8];
            ldB2(15, b2r);
            const unsigned short* hr = &hs_all[w][15 & 1][0];
            const bf16x8 a20 = *(const bf16x8*)(hr + lrow * HSP + lgrp * 8);
            const bf16x8 a21 = *(const bf16x8*)(hr + (16 + lrow) * HSP + lgrp * 8);
#pragma unroll
            for (int nt2 = 0; nt2 < 8; ++nt2) {
                acc2[0][nt2] = __builtin_amdgcn_mfma_f32_16x16x32_bf16(a20, b2r[nt2], acc2[0][nt2], 0, 0, 0);
                acc2[1][nt2] = __builtin_amdgcn_mfma_f32_16x16x32_bf16(a21, b2r[nt2], acc2[1][nt2], 0, 0, 0);
            }
        }

        // store: D row = mt*16 + lgrp*4 + r, col = nt2*16 + lrow
#pragma unroll
        for (int mt = 0; mt < 2; ++mt)
#pragma unroll
            for (int nt2 = 0; nt2 < 8; ++nt2)
#pragma unroll
                for (int r = 0; r < 4; ++r)
                    out[(size_t)(rb + mt * 16 + lgrp * 4 + r) * 128 + nt2 * 16 + lrow] =
                        acc2[mt][nt2][r];
    }
}

extern "C" void kernel_launch(void* const* d_in, const int* in_sizes, int n_in,
                              void* d_out, int out_size, void* d_ws, size_t ws_size,
                              hipStream_t stream)
{
    const float* x  = (const float*)d_in[0];
    const int* hyper = (const int*)d_in[1];
    const float* W1 = (const float*)d_in[2];
    const float* b1 = (const float*)d_in[3];
    const float* W2 = (const float*)d_in[4];
    const float* b2 = (const float*)d_in[5];
    const int nnz = in_sizes[0] / D_IN;
    const int* seg = hyper + nnz;   // hyperedge_index[1]

    char* ws = (char*)d_ws;
    int* cur    = (int*)(ws + 0x0000000);            // E x 16 ints (line-padded), 8 MB
    int* bucket = (int*)(ws + 0x0800000);            // E x CAP ints, 32 MB
    unsigned short* w1b = (unsigned short*)(ws + 0x2800000);   // 128 KB
    unsigned short* w2b = (unsigned short*)(ws + 0x2820000);   // 128 KB
    unsigned short* meanb = (unsigned short*)(ws + 0x2840000); // E x 128 bf16, 32 MB
    int* cur_d    = (int*)(ws + 0x4840000);          // dummy, 8 MB
    int* bucket_d = (int*)(ws + 0x5040000);          // dummy, 32 MB
    unsigned short* meanb_d = (unsigned short*)(ws + 0x7040000); // dummy, 32 MB
    float* out = (float*)d_out;

    // ---- real pipeline ----
    hipLaunchKernelGGL(zero16, dim3(2048), dim3(256), 0, stream, cur);
    hipLaunchKernelGGL(bucketfill_kernel, dim3(nnz / 1024), dim3(256), 0, stream,
                       seg, cur, bucket, nnz);
    hipLaunchKernelGGL(convw_kernel, dim3((D_IN * D_HID + D_HID * D_OUT) / 256), dim3(256), 0,
                       stream, W1, W2, w1b, w2b);
    hipLaunchKernelGGL(gather_kernel, dim3(E_EDGES / 64), dim3(256), 0, stream,
                       x, bucket, cur, meanb, 1);
    hipLaunchKernelGGL(gemm_kernel, dim3(E_EDGES / 128), dim3(256), 0, stream,
                       meanb, w1b, w2b, b1, b2, out, 1);

    // ---- probes (dummy / idempotent targets; d_out unaffected) ----
    hipLaunchKernelGGL(zero16, dim3(2048), dim3(256), 0, stream, cur_d);
    hipLaunchKernelGGL(probe_bucketfill, dim3(nnz / 1024), dim3(256), 0, stream,
                       seg, cur_d, bucket_d, nnz, 6);
    hipLaunchKernelGGL(gather_kernel, dim3(E_EDGES / 64), dim3(256), 0, stream,
                       x, bucket, cur, meanb_d, 3);
    hipLaunchKernelGGL(gemm_kernel, dim3(E_EDGES / 128), dim3(256), 0, stream,
                       meanb, w1b, w2b, b1, b2, out, 16);
}

// Round 9
// 4339.901 us; speedup vs baseline: 1.0743x; 1.0743x over previous
//
#include <hip/hip_runtime.h>

#define E_EDGES 131072
#define D_IN 128
#define D_HID 512
#define D_OUT 128
#define CAP 64          // bucket capacity (Poisson(16); P(count>56) ~ 7e-14; clamped)
#define HSP 40          // hslice row pitch in ushorts (80 B): bank-spreading, b128-safe

typedef __bf16 bf16x8 __attribute__((ext_vector_type(8)));
typedef float f32x4 __attribute__((ext_vector_type(4)));

__device__ __forceinline__ unsigned short f2bf(float f) {
    unsigned int u = __float_as_uint(f);
    unsigned int r = (u + 0x7FFFu + ((u >> 16) & 1u)) >> 16;
    return (unsigned short)r;
}

__global__ void zero16(int* __restrict__ p) {
    int i = blockIdx.x * blockDim.x + threadIdx.x;
    ((int4*)p)[i] = make_int4(0, 0, 0, 0);
}

// Single-pass bucket scatter. cur line-padded: counter e at cur[e*16].
__global__ void bucketfill_kernel(const int* __restrict__ seg, int* __restrict__ cur,
                                  int* __restrict__ bucket, int nnz) {
    int i = blockIdx.x * blockDim.x + threadIdx.x;
    if (i * 4 < nnz) {
        int4 s = ((const int4*)seg)[i];
        int p0 = atomicAdd(&cur[s.x * 16], 1);
        int p1 = atomicAdd(&cur[s.y * 16], 1);
        int p2 = atomicAdd(&cur[s.z * 16], 1);
        int p3 = atomicAdd(&cur[s.w * 16], 1);
        if (p0 < CAP) bucket[s.x * CAP + p0] = i * 4;
        if (p1 < CAP) bucket[s.y * CAP + p1] = i * 4 + 1;
        if (p2 < CAP) bucket[s.z * CAP + p2] = i * 4 + 2;
        if (p3 < CAP) bucket[s.w * CAP + p3] = i * 4 + 3;
    }
}

__global__ void probe_bucketfill(const int* __restrict__ seg, int* __restrict__ cur_d,
                                 int* __restrict__ bucket_d, int nnz, int reps) {
    int i = blockIdx.x * blockDim.x + threadIdx.x;
    if (i * 4 < nnz) {
        int4 s = ((const int4*)seg)[i];
#pragma unroll 1
        for (int rep = 0; rep < reps; ++rep) {
            int p0 = atomicAdd(&cur_d[s.x * 16], 1);
            int p1 = atomicAdd(&cur_d[s.y * 16], 1);
            int p2 = atomicAdd(&cur_d[s.z * 16], 1);
            int p3 = atomicAdd(&cur_d[s.w * 16], 1);
            bucket_d[s.x * CAP + (p0 & 31)] = i * 4;
            bucket_d[s.y * CAP + (p1 & 31)] = i * 4 + 1;
            bucket_d[s.z * CAP + (p2 & 31)] = i * 4 + 2;
            bucket_d[s.w * CAP + (p3 & 31)] = i * 4 + 3;
            asm volatile("" ::: "memory");
        }
    }
}

// W1 [128][512] fp32 -> w1b = bf16 W1^T [512][128]; W2 [512][128] -> w2b [128][512]
__global__ void convw_kernel(const float* __restrict__ W1, const float* __restrict__ W2,
                             unsigned short* __restrict__ w1b, unsigned short* __restrict__ w2b) {
    int i = blockIdx.x * blockDim.x + threadIdx.x;
    if (i < D_IN * D_HID) {
        int n = i >> 7, k = i & 127;
        w1b[i] = f2bf(W1[(size_t)k * D_HID + n]);
    } else {
        int i2 = i - D_IN * D_HID;
        int n = i2 >> 9, k = i2 & 511;
        w2b[i2] = f2bf(W2[(size_t)k * D_OUT + n]);
    }
}

// Gather-mean from buckets. 4 waves/block, wave owns 16 edges.
__global__ __launch_bounds__(256) void gather_kernel(
    const float* __restrict__ x, const int* __restrict__ bucket,
    const int* __restrict__ cur, unsigned short* __restrict__ meanb, int reps)
{
    const int tid  = threadIdx.x;
    const int lane = tid & 63;
    const int w    = tid >> 6;
    const int tile = blockIdx.x;
    const int e0   = tile * 64 + w * 16;

    const int c  = lane & 31;
    const int rr = lane >> 5;
    const char* xb = (const char*)x + c * 16;

    int nval = min(cur[(e0 + (lane & 15)) * 16], CAP);

#pragma unroll 1
    for (int rep = 0; rep < reps; ++rep) {
        for (int el = 0; el < 16; ++el) {
            const int n = __shfl(nval, el);
            const int* ce = bucket + (size_t)(e0 + el) * CAP;
            f32x4 a0 = {0.f, 0.f, 0.f, 0.f};
            f32x4 a1 = a0, a2 = a0, a3 = a0, a4 = a0, a5 = a0, a6 = a0, a7 = a0;
            for (int j = 0; j < n; j += 16) {
#define GSLOT(k, acc)                                                        \
                {                                                            \
                    const int jj = j + 2 * (k) + rr;                         \
                    if (jj < n) {                                            \
                        const int idx = ce[jj];                              \
                        f32x4 v = __builtin_nontemporal_load(                \
                            (const f32x4*)(xb + (size_t)idx * 512));         \
                        acc += v;                                            \
                    }                                                        \
                }
                GSLOT(0, a0) GSLOT(1, a1) GSLOT(2, a2) GSLOT(3, a3)
                GSLOT(4, a4) GSLOT(5, a5) GSLOT(6, a6) GSLOT(7, a7)
#undef GSLOT
            }
            f32x4 tot = ((a0 + a1) + (a2 + a3)) + ((a4 + a5) + (a6 + a7));
            tot[0] += __shfl_xor(tot[0], 32);
            tot[1] += __shfl_xor(tot[1], 32);
            tot[2] += __shfl_xor(tot[2], 32);
            tot[3] += __shfl_xor(tot[3], 32);
            const float scale = 1.0f / (float)(n > 0 ? n : 1);
            if (lane < 32) {
                unsigned int d0 = (unsigned)f2bf(tot[0] * scale) | ((unsigned)f2bf(tot[1] * scale) << 16);
                unsigned int d1 = (unsigned)f2bf(tot[2] * scale) | ((unsigned)f2bf(tot[3] * scale) << 16);
                *(uint2*)((char*)meanb + (size_t)(e0 + el) * 256 + c * 8) = make_uint2(d0, d1);
            }
        }
    }
}

// Fused MLP GEMM with LDS-resident weight slices.
// 8 waves x 32 rows = 256 rows/block, grid 512. 4 phases of 128 hidden cols:
// per phase stage w1-slice(32KB)+w2-kslice(32KB) into double-buffered LDS
// (T14 reg-staged, XOR-swizzled), GEMM1 -> hslice -> GEMM2 accumulate.
__global__ __launch_bounds__(512, 2) void gemm_kernel(
    const unsigned short* __restrict__ meanb, const unsigned short* __restrict__ w1b,
    const unsigned short* __restrict__ w2b, const float* __restrict__ b1,
    const float* __restrict__ b2, float* __restrict__ out, int reps)
{
    __shared__ unsigned short wbuf[2][2][128 * 128];   // [buf][0=w1s,1=w2s], 128 KB
    __shared__ unsigned short hsl_all[8][32 * HSP];    // per-wave, 20 KB

    const int tid  = threadIdx.x;
    const int lane = tid & 63;
    const int w    = tid >> 6;
    const int tile = blockIdx.x;
    const int rb   = tile * 256 + w * 32;

    const int lrow = lane & 15;
    const int lgrp = lane >> 4;
    const int swz  = (lrow & 7) << 4;       // read-side XOR (r&7 == lrow&7)

    // staging addr components (per thread, 4 iters per region)
    int sL[4], sR[4], sCB[4], sSB[4];
#pragma unroll
    for (int i = 0; i < 4; ++i) {
        sL[i]  = i * 8192 + tid * 16;       // linear byte offset in 32 KB region
        sR[i]  = sL[i] >> 8;                // row
        sCB[i] = sL[i] & 255;               // col byte
        sSB[i] = sR[i] * 256 + (sCB[i] ^ ((sR[i] & 7) << 4));  // swizzled LDS byte
    }

    float bias2[8];
#pragma unroll
    for (int nt2 = 0; nt2 < 8; ++nt2) bias2[nt2] = b2[nt2 * 16 + lrow];

    bf16x8 afrag[2][4];
#pragma unroll
    for (int mt = 0; mt < 2; ++mt)
#pragma unroll
        for (int kk = 0; kk < 4; ++kk)
            afrag[mt][kk] = *(const bf16x8*)(meanb +
                (size_t)(rb + mt * 16 + lrow) * 128 + kk * 32 + lgrp * 8);

#define STAGE_LOAD(ph, sr)                                                     \
    {                                                                          \
        _Pragma("unroll")                                                      \
        for (int i = 0; i < 4; ++i)                                            \
            sr[i] = *(const uint4*)((const char*)w1b + (ph) * 32768 + sL[i]);  \
        _Pragma("unroll")                                                      \
        for (int i = 0; i < 4; ++i)                                            \
            sr[4 + i] = *(const uint4*)((const char*)w2b + sR[i] * 1024 +      \
                                        (ph) * 256 + sCB[i]);                  \
    }
#define STAGE_WRITE(buf, sr)                                                   \
    {                                                                          \
        char* b0 = (char*)&wbuf[buf][0][0];                                    \
        char* b1p = (char*)&wbuf[buf][1][0];                                   \
        _Pragma("unroll")                                                      \
        for (int i = 0; i < 4; ++i) {                                          \
            *(uint4*)(b0 + sSB[i]) = sr[i];                                    \
            *(uint4*)(b1p + sSB[i]) = sr[4 + i];                               \
        }                                                                      \
    }

    f32x4 acc2[2][8];
    unsigned short* hw = &hsl_all[w][0];

    auto compute_phase = [&](int ph, int buf) {
        const char* w1L = (const char*)&wbuf[buf][0][0];
        const char* w2L = (const char*)&wbuf[buf][1][0];
        float b1v[8];
#pragma unroll
        for (int q = 0; q < 8; ++q) b1v[q] = b1[ph * 128 + q * 16 + lrow];
#pragma unroll
        for (int ntp = 0; ntp < 4; ++ntp) {
#pragma unroll
            for (int half = 0; half < 2; ++half) {
                const int ntq = ntp * 2 + half;
                f32x4 acc0 = {b1v[ntq], b1v[ntq], b1v[ntq], b1v[ntq]};
                f32x4 acc1 = acc0;
#pragma unroll
                for (int kk = 0; kk < 4; ++kk) {
                    const int r = ntq * 16 + lrow;
                    const bf16x8 bb = *(const bf16x8*)(w1L + r * 256 +
                        ((kk * 64 + lgrp * 16) ^ swz));
                    acc0 = __builtin_amdgcn_mfma_f32_16x16x32_bf16(afrag[0][kk], bb, acc0, 0, 0, 0);
                    acc1 = __builtin_amdgcn_mfma_f32_16x16x32_bf16(afrag[1][kk], bb, acc1, 0, 0, 0);
                }
#pragma unroll
                for (int r4 = 0; r4 < 4; ++r4) {
                    hw[(lgrp * 4 + r4) * HSP + half * 16 + lrow]      = f2bf(fmaxf(acc0[r4], 0.f));
                    hw[(16 + lgrp * 4 + r4) * HSP + half * 16 + lrow] = f2bf(fmaxf(acc1[r4], 0.f));
                }
            }
            const bf16x8 a20 = *(const bf16x8*)(hw + lrow * HSP + lgrp * 8);
            const bf16x8 a21 = *(const bf16x8*)(hw + (16 + lrow) * HSP + lgrp * 8);
#pragma unroll
            for (int nt2 = 0; nt2 < 8; ++nt2) {
                const int r = nt2 * 16 + lrow;
                const bf16x8 bb = *(const bf16x8*)(w2L + r * 256 +
                    ((ntp * 64 + lgrp * 16) ^ swz));
                acc2[0][nt2] = __builtin_amdgcn_mfma_f32_16x16x32_bf16(a20, bb, acc2[0][nt2], 0, 0, 0);
                acc2[1][nt2] = __builtin_amdgcn_mfma_f32_16x16x32_bf16(a21, bb, acc2[1][nt2], 0, 0, 0);
            }
        }
    };

#pragma unroll 1
    for (int rep = 0; rep < reps; ++rep) {
#pragma unroll
        for (int mt = 0; mt < 2; ++mt)
#pragma unroll
            for (int nt2 = 0; nt2 < 8; ++nt2) {
                f32x4 bv = {bias2[nt2], bias2[nt2], bias2[nt2], bias2[nt2]};
                acc2[mt][nt2] = bv;
            }

        uint4 sA[8], sB[8];
        STAGE_LOAD(0, sA);
        asm volatile("s_waitcnt vmcnt(0)" ::: "memory");
        STAGE_WRITE(0, sA);
        STAGE_LOAD(1, sB);
        asm volatile("s_waitcnt lgkmcnt(0)" ::: "memory");
        __builtin_amdgcn_s_barrier();

        compute_phase(0, 0);
        asm volatile("s_waitcnt vmcnt(0)" ::: "memory");
        STAGE_WRITE(1, sB);
        STAGE_LOAD(2, sA);
        asm volatile("s_waitcnt lgkmcnt(0)" ::: "memory");
        __builtin_amdgcn_s_barrier();

        compute_phase(1, 1);
        asm volatile("s_waitcnt vmcnt(0)" ::: "memory");
        STAGE_WRITE(0, sA);
        STAGE_LOAD(3, sB);
        asm volatile("s_waitcnt lgkmcnt(0)" ::: "memory");
        __builtin_amdgcn_s_barrier();

        compute_phase(2, 0);
        asm volatile("s_waitcnt vmcnt(0)" ::: "memory");
        STAGE_WRITE(1, sB);
        asm volatile("s_waitcnt lgkmcnt(0)" ::: "memory");
        __builtin_amdgcn_s_barrier();

        compute_phase(3, 1);

#pragma unroll
        for (int mt = 0; mt < 2; ++mt)
#pragma unroll
            for (int nt2 = 0; nt2 < 8; ++nt2)
#pragma unroll
                for (int r4 = 0; r4 < 4; ++r4)
                    out[(size_t)(rb + mt * 16 + lgrp * 4 + r4) * 128 + nt2 * 16 + lrow] =
                        acc2[mt][nt2][r4];
    }
#undef STAGE_LOAD
#undef STAGE_WRITE
}

extern "C" void kernel_launch(void* const* d_in, const int* in_sizes, int n_in,
                              void* d_out, int out_size, void* d_ws, size_t ws_size,
                              hipStream_t stream)
{
    const float* x  = (const float*)d_in[0];
    const int* hyper = (const int*)d_in[1];
    const float* W1 = (const float*)d_in[2];
    const float* b1 = (const float*)d_in[3];
    const float* W2 = (const float*)d_in[4];
    const float* b2 = (const float*)d_in[5];
    const int nnz = in_sizes[0] / D_IN;
    const int* seg = hyper + nnz;

    char* ws = (char*)d_ws;
    int* cur    = (int*)(ws + 0x0000000);            // E x 16 ints, 8 MB
    int* bucket = (int*)(ws + 0x0800000);            // E x CAP ints, 32 MB
    unsigned short* w1b = (unsigned short*)(ws + 0x2800000);   // 128 KB
    unsigned short* w2b = (unsigned short*)(ws + 0x2820000);   // 128 KB
    unsigned short* meanb = (unsigned short*)(ws + 0x2840000); // 32 MB
    int* cur_d    = (int*)(ws + 0x4840000);          // dummy, 8 MB
    int* bucket_d = (int*)(ws + 0x5040000);          // dummy, 32 MB
    unsigned short* meanb_d = (unsigned short*)(ws + 0x7040000); // dummy, 32 MB
    float* out = (float*)d_out;

    // ---- real pipeline ----
    hipLaunchKernelGGL(zero16, dim3(2048), dim3(256), 0, stream, cur);
    hipLaunchKernelGGL(bucketfill_kernel, dim3(nnz / 1024), dim3(256), 0, stream,
                       seg, cur, bucket, nnz);
    hipLaunchKernelGGL(convw_kernel, dim3((D_IN * D_HID + D_HID * D_OUT) / 256), dim3(256), 0,
                       stream, W1, W2, w1b, w2b);
    hipLaunchKernelGGL(gather_kernel, dim3(E_EDGES / 64), dim3(256), 0, stream,
                       x, bucket, cur, meanb, 1);
    hipLaunchKernelGGL(gemm_kernel, dim3(E_EDGES / 256), dim3(512), 0, stream,
                       meanb, w1b, w2b, b1, b2, out, 1);

    // ---- probes (dummy / idempotent targets; d_out unaffected) ----
    hipLaunchKernelGGL(zero16, dim3(2048), dim3(256), 0, stream, cur_d);
    hipLaunchKernelGGL(probe_bucketfill, dim3(nnz / 1024), dim3(256), 0, stream,
                       seg, cur_d, bucket_d, nnz, 6);
    hipLaunchKernelGGL(gather_kernel, dim3(E_EDGES / 64), dim3(256), 0, stream,
                       x, bucket, cur, meanb_d, 6);
    hipLaunchKernelGGL(gemm_kernel, dim3(E_EDGES / 256), dim3(512), 0, stream,
                       meanb, w1b, w2b, b1, b2, out, 16);
}

// Round 10
// 2977.631 us; speedup vs baseline: 1.5658x; 1.4575x over previous
//
#include <hip/hip_runtime.h>

#define E_EDGES 131072
#define D_IN 128
#define D_HID 512
#define D_OUT 128
#define CAP 64          // bucket capacity (Poisson(16); P(count>56) ~ 7e-14; clamped)
#define HSP 40          // hslice row pitch in ushorts (80 B): bank-spreading, b128-safe

typedef __bf16 bf16x8 __attribute__((ext_vector_type(8)));
typedef float f32x4 __attribute__((ext_vector_type(4)));

__device__ __forceinline__ unsigned short f2bf(float f) {
    unsigned int u = __float_as_uint(f);
    unsigned int r = (u + 0x7FFFu + ((u >> 16) & 1u)) >> 16;
    return (unsigned short)r;
}

__global__ void zero16(int* __restrict__ p) {
    int i = blockIdx.x * blockDim.x + threadIdx.x;
    ((int4*)p)[i] = make_int4(0, 0, 0, 0);
}

// Single-pass bucket scatter. cur line-padded: counter e at cur[e*16].
__global__ void bucketfill_kernel(const int* __restrict__ seg, int* __restrict__ cur,
                                  int* __restrict__ bucket, int nnz) {
    int i = blockIdx.x * blockDim.x + threadIdx.x;
    if (i * 4 < nnz) {
        int4 s = ((const int4*)seg)[i];
        int p0 = atomicAdd(&cur[s.x * 16], 1);
        int p1 = atomicAdd(&cur[s.y * 16], 1);
        int p2 = atomicAdd(&cur[s.z * 16], 1);
        int p3 = atomicAdd(&cur[s.w * 16], 1);
        if (p0 < CAP) bucket[s.x * CAP + p0] = i * 4;
        if (p1 < CAP) bucket[s.y * CAP + p1] = i * 4 + 1;
        if (p2 < CAP) bucket[s.z * CAP + p2] = i * 4 + 2;
        if (p3 < CAP) bucket[s.w * CAP + p3] = i * 4 + 3;
    }
}

// W1 [128][512] fp32 -> w1b = bf16 W1^T [512][128]; W2 [512][128] -> w2b [128][512]
__global__ void convw_kernel(const float* __restrict__ W1, const float* __restrict__ W2,
                             unsigned short* __restrict__ w1b, unsigned short* __restrict__ w2b) {
    int i = blockIdx.x * blockDim.x + threadIdx.x;
    if (i < D_IN * D_HID) {
        int n = i >> 7, k = i & 127;
        w1b[i] = f2bf(W1[(size_t)k * D_HID + n]);
    } else {
        int i2 = i - D_IN * D_HID;
        int n = i2 >> 9, k = i2 & 511;
        w2b[i2] = f2bf(W2[(size_t)k * D_OUT + n]);
    }
}

// Gather-mean from buckets. 4 waves/block, wave owns 16 edges.
// DRAM-efficiency-bound on random 512B reads (measured 2.3 TB/s, occ 88%).
__global__ __launch_bounds__(256) void gather_kernel(
    const float* __restrict__ x, const int* __restrict__ bucket,
    const int* __restrict__ cur, unsigned short* __restrict__ meanb, int reps)
{
    const int tid  = threadIdx.x;
    const int lane = tid & 63;
    const int w    = tid >> 6;
    const int tile = blockIdx.x;
    const int e0   = tile * 64 + w * 16;

    const int c  = lane & 31;
    const int rr = lane >> 5;
    const char* xb = (const char*)x + c * 16;

    int nval = min(cur[(e0 + (lane & 15)) * 16], CAP);

#pragma unroll 1
    for (int rep = 0; rep < reps; ++rep) {
        for (int el = 0; el < 16; ++el) {
            const int n = __shfl(nval, el);
            const int* ce = bucket + (size_t)(e0 + el) * CAP;
            f32x4 a0 = {0.f, 0.f, 0.f, 0.f};
            f32x4 a1 = a0, a2 = a0, a3 = a0, a4 = a0, a5 = a0, a6 = a0, a7 = a0;
            for (int j = 0; j < n; j += 16) {
#define GSLOT(k, acc)                                                        \
                {                                                            \
                    const int jj = j + 2 * (k) + rr;                         \
                    if (jj < n) {                                            \
                        const int idx = ce[jj];                              \
                        f32x4 v = __builtin_nontemporal_load(                \
                            (const f32x4*)(xb + (size_t)idx * 512));         \
                        acc += v;                                            \
                    }                                                        \
                }
                GSLOT(0, a0) GSLOT(1, a1) GSLOT(2, a2) GSLOT(3, a3)
                GSLOT(4, a4) GSLOT(5, a5) GSLOT(6, a6) GSLOT(7, a7)
#undef GSLOT
            }
            f32x4 tot = ((a0 + a1) + (a2 + a3)) + ((a4 + a5) + (a6 + a7));
            tot[0] += __shfl_xor(tot[0], 32);
            tot[1] += __shfl_xor(tot[1], 32);
            tot[2] += __shfl_xor(tot[2], 32);
            tot[3] += __shfl_xor(tot[3], 32);
            const float scale = 1.0f / (float)(n > 0 ? n : 1);
            if (lane < 32) {
                unsigned int d0 = (unsigned)f2bf(tot[0] * scale) | ((unsigned)f2bf(tot[1] * scale) << 16);
                unsigned int d1 = (unsigned)f2bf(tot[2] * scale) | ((unsigned)f2bf(tot[3] * scale) << 16);
                *(uint2*)((char*)meanb + (size_t)(e0 + el) * 256 + c * 8) = make_uint2(d0, d1);
            }
        }
    }
}

// Pipelined fused MLP GEMM, register-direct weights.
// Streaming data (meanb in, out out) uses NONTEMPORAL ops so the 256 KB of
// weights stays L2-resident (round-8 counter showed 1.12 GB weight re-fetch
// from L3 when meanb streamed through L2). 3 waves/SIMD hide L2 latency.
__global__ __launch_bounds__(256, 3) void gemm_kernel(
    const unsigned short* __restrict__ meanb, const unsigned short* __restrict__ w1b,
    const unsigned short* __restrict__ w2b, const float* __restrict__ b1,
    const float* __restrict__ b2, float* __restrict__ out, int reps)
{
    __shared__ unsigned short hs_all[4][2][32 * HSP];   // 4 waves x 2 bufs x 2560B = 20 KB

    const int tid  = threadIdx.x;
    const int lane = tid & 63;
    const int w    = tid >> 6;
    const int tile = blockIdx.x;            // 0..1023
    const int rb   = tile * 128 + w * 32;   // wave's 32 rows

    const int lrow = lane & 15;
    const int lgrp = lane >> 4;

    float bias2[8];
#pragma unroll
    for (int nt2 = 0; nt2 < 8; ++nt2) bias2[nt2] = b2[nt2 * 16 + lrow];

    auto ldB1 = [&](int ntp, bf16x8 (&b1r)[2][4], float (&bia)[2]) {
#pragma unroll
        for (int half = 0; half < 2; ++half) {
            const int nt = ntp * 2 + half;
            bia[half] = b1[nt * 16 + lrow];
#pragma unroll
            for (int kk = 0; kk < 4; ++kk)
                b1r[half][kk] = *(const bf16x8*)(w1b +
                    (size_t)(nt * 16 + lrow) * 128 + kk * 32 + lgrp * 8);
        }
    };
    auto ldB2 = [&](int ntp, bf16x8 (&b2r)[8]) {
#pragma unroll
        for (int nt2 = 0; nt2 < 8; ++nt2)
            b2r[nt2] = *(const bf16x8*)(w2b +
                (size_t)(nt2 * 16 + lrow) * 512 + ntp * 32 + lgrp * 8);
    };

#pragma unroll 1
    for (int rep = 0; rep < reps; ++rep) {
        bf16x8 afrag[2][4];
#pragma unroll
        for (int mt = 0; mt < 2; ++mt)
#pragma unroll
            for (int kk = 0; kk < 4; ++kk)
                afrag[mt][kk] = __builtin_nontemporal_load((const bf16x8*)(meanb +
                    (size_t)(rb + mt * 16 + lrow) * 128 + kk * 32 + lgrp * 8));

        f32x4 acc2[2][8];
#pragma unroll
        for (int mt = 0; mt < 2; ++mt)
#pragma unroll
            for (int nt2 = 0; nt2 < 8; ++nt2) {
                f32x4 bv = {bias2[nt2], bias2[nt2], bias2[nt2], bias2[nt2]};
                acc2[mt][nt2] = bv;
            }

        auto g1wr = [&](int ntp, bf16x8 (&b1r)[2][4], float (&bia)[2]) {
            unsigned short* hw = &hs_all[w][ntp & 1][0];
#pragma unroll
            for (int half = 0; half < 2; ++half) {
                f32x4 acc0 = {bia[half], bia[half], bia[half], bia[half]};
                f32x4 acc1 = acc0;
#pragma unroll
                for (int kk = 0; kk < 4; ++kk) {
                    acc0 = __builtin_amdgcn_mfma_f32_16x16x32_bf16(afrag[0][kk], b1r[half][kk], acc0, 0, 0, 0);
                    acc1 = __builtin_amdgcn_mfma_f32_16x16x32_bf16(afrag[1][kk], b1r[half][kk], acc1, 0, 0, 0);
                }
#pragma unroll
                for (int r = 0; r < 4; ++r) {
                    hw[(lgrp * 4 + r) * HSP + half * 16 + lrow]      = f2bf(fmaxf(acc0[r], 0.f));
                    hw[(16 + lgrp * 4 + r) * HSP + half * 16 + lrow] = f2bf(fmaxf(acc1[r], 0.f));
                }
            }
        };

        // prologue
        {
            bf16x8 b1r[2][4]; float bia[2];
            ldB1(0, b1r, bia);
            g1wr(0, b1r, bia);
        }
        // main: ntp = 0..14
#pragma unroll 1
        for (int ntp = 0; ntp < 15; ++ntp) {
            bf16x8 nb1[2][4]; float nbia[2];
            ldB1(ntp + 1, nb1, nbia);
            bf16x8 b2r[8];
            ldB2(ntp, b2r);
            const unsigned short* hr = &hs_all[w][ntp & 1][0];
            const bf16x8 a20 = *(const bf16x8*)(hr + lrow * HSP + lgrp * 8);
            const bf16x8 a21 = *(const bf16x8*)(hr + (16 + lrow) * HSP + lgrp * 8);
            g1wr(ntp + 1, nb1, nbia);
#pragma unroll
            for (int nt2 = 0; nt2 < 8; ++nt2) {
                acc2[0][nt2] = __builtin_amdgcn_mfma_f32_16x16x32_bf16(a20, b2r[nt2], acc2[0][nt2], 0, 0, 0);
                acc2[1][nt2] = __builtin_amdgcn_mfma_f32_16x16x32_bf16(a21, b2r[nt2], acc2[1][nt2], 0, 0, 0);
            }
        }
        // epilogue slice 15
        {
            bf16x8 b2r[8];
            ldB2(15, b2r);
            const unsigned short* hr = &hs_all[w][15 & 1][0];
            const bf16x8 a20 = *(const bf16x8*)(hr + lrow * HSP + lgrp * 8);
            const bf16x8 a21 = *(const bf16x8*)(hr + (16 + lrow) * HSP + lgrp * 8);
#pragma unroll
            for (int nt2 = 0; nt2 < 8; ++nt2) {
                acc2[0][nt2] = __builtin_amdgcn_mfma_f32_16x16x32_bf16(a20, b2r[nt2], acc2[0][nt2], 0, 0, 0);
                acc2[1][nt2] = __builtin_amdgcn_mfma_f32_16x16x32_bf16(a21, b2r[nt2], acc2[1][nt2], 0, 0, 0);
            }
        }

        // store (nontemporal: don't pollute L2)
#pragma unroll
        for (int mt = 0; mt < 2; ++mt)
#pragma unroll
            for (int nt2 = 0; nt2 < 8; ++nt2)
#pragma unroll
                for (int r = 0; r < 4; ++r)
                    __builtin_nontemporal_store(acc2[mt][nt2][r],
                        &out[(size_t)(rb + mt * 16 + lgrp * 4 + r) * 128 + nt2 * 16 + lrow]);
    }
}

extern "C" void kernel_launch(void* const* d_in, const int* in_sizes, int n_in,
                              void* d_out, int out_size, void* d_ws, size_t ws_size,
                              hipStream_t stream)
{
    const float* x  = (const float*)d_in[0];
    const int* hyper = (const int*)d_in[1];
    const float* W1 = (const float*)d_in[2];
    const float* b1 = (const float*)d_in[3];
    const float* W2 = (const float*)d_in[4];
    const float* b2 = (const float*)d_in[5];
    const int nnz = in_sizes[0] / D_IN;
    const int* seg = hyper + nnz;

    char* ws = (char*)d_ws;
    int* cur    = (int*)(ws + 0x0000000);            // E x 16 ints, 8 MB
    int* bucket = (int*)(ws + 0x0800000);            // E x CAP ints, 32 MB
    unsigned short* w1b = (unsigned short*)(ws + 0x2800000);   // 128 KB
    unsigned short* w2b = (unsigned short*)(ws + 0x2820000);   // 128 KB
    unsigned short* meanb = (unsigned short*)(ws + 0x2840000); // 32 MB
    float* out = (float*)d_out;

    // ---- real pipeline ----
    hipLaunchKernelGGL(zero16, dim3(2048), dim3(256), 0, stream, cur);
    hipLaunchKernelGGL(bucketfill_kernel, dim3(nnz / 1024), dim3(256), 0, stream,
                       seg, cur, bucket, nnz);
    hipLaunchKernelGGL(convw_kernel, dim3((D_IN * D_HID + D_HID * D_OUT) / 256), dim3(256), 0,
                       stream, W1, W2, w1b, w2b);
    hipLaunchKernelGGL(gather_kernel, dim3(E_EDGES / 64), dim3(256), 0, stream,
                       x, bucket, cur, meanb, 1);
    hipLaunchKernelGGL(gemm_kernel, dim3(E_EDGES / 128), dim3(256), 0, stream,
                       meanb, w1b, w2b, b1, b2, out, 1);

    // ---- probe: gemm x16 (idempotent, rewrites identical out) ----
    hipLaunchKernelGGL(gemm_kernel, dim3(E_EDGES / 128), dim3(256), 0, stream,
                       meanb, w1b, w2b, b1, b2, out, 16);
}

// Round 11
// 1974.068 us; speedup vs baseline: 2.3619x; 1.5084x over previous
//
#include <hip/hip_runtime.h>

#define E_EDGES 131072
#define D_IN 128
#define D_HID 512
#define D_OUT 128
#define CAP 64          // bucket capacity (Poisson(16); P(count>56) ~ 7e-14; clamped)
#define HSP 40          // hslice row pitch in ushorts (80 B): bank-spreading, b128-safe

typedef __bf16 bf16x8 __attribute__((ext_vector_type(8)));
typedef float f32x4 __attribute__((ext_vector_type(4)));

__device__ __forceinline__ unsigned short f2bf(float f) {
    unsigned int u = __float_as_uint(f);
    unsigned int r = (u + 0x7FFFu + ((u >> 16) & 1u)) >> 16;
    return (unsigned short)r;
}

__global__ void zero16(int* __restrict__ p) {
    int i = blockIdx.x * blockDim.x + threadIdx.x;
    ((int4*)p)[i] = make_int4(0, 0, 0, 0);
}

// Single-pass bucket scatter. cur line-padded: counter e at cur[e*16].
__global__ void bucketfill_kernel(const int* __restrict__ seg, int* __restrict__ cur,
                                  int* __restrict__ bucket, int nnz) {
    int i = blockIdx.x * blockDim.x + threadIdx.x;
    if (i * 4 < nnz) {
        int4 s = ((const int4*)seg)[i];
        int p0 = atomicAdd(&cur[s.x * 16], 1);
        int p1 = atomicAdd(&cur[s.y * 16], 1);
        int p2 = atomicAdd(&cur[s.z * 16], 1);
        int p3 = atomicAdd(&cur[s.w * 16], 1);
        if (p0 < CAP) bucket[s.x * CAP + p0] = i * 4;
        if (p1 < CAP) bucket[s.y * CAP + p1] = i * 4 + 1;
        if (p2 < CAP) bucket[s.z * CAP + p2] = i * 4 + 2;
        if (p3 < CAP) bucket[s.w * CAP + p3] = i * 4 + 3;
    }
}

// W1 [128][512] fp32 -> w1b = bf16 W1^T [512][128]; W2 [512][128] -> w2b [128][512]
__global__ void convw_kernel(const float* __restrict__ W1, const float* __restrict__ W2,
                             unsigned short* __restrict__ w1b, unsigned short* __restrict__ w2b) {
    int i = blockIdx.x * blockDim.x + threadIdx.x;
    if (i < D_IN * D_HID) {
        int n = i >> 7, k = i & 127;
        w1b[i] = f2bf(W1[(size_t)k * D_HID + n]);
    } else {
        int i2 = i - D_IN * D_HID;
        int n = i2 >> 9, k = i2 & 511;
        w2b[i2] = f2bf(W2[(size_t)k * D_OUT + n]);
    }
}

// Gather-mean from buckets. 4 waves/block, wave owns 16 edges.
// Plain (cached) x loads: L3 absorbs ~50% of the 1GB re-read.
__global__ __launch_bounds__(256) void gather_kernel(
    const float* __restrict__ x, const int* __restrict__ bucket,
    const int* __restrict__ cur, unsigned short* __restrict__ meanb, int reps)
{
    const int tid  = threadIdx.x;
    const int lane = tid & 63;
    const int w    = tid >> 6;
    const int tile = blockIdx.x;
    const int e0   = tile * 64 + w * 16;

    const int c  = lane & 31;
    const int rr = lane >> 5;
    const char* xb = (const char*)x + c * 16;

    int nval = min(cur[(e0 + (lane & 15)) * 16], CAP);

#pragma unroll 1
    for (int rep = 0; rep < reps; ++rep) {
        for (int el = 0; el < 16; ++el) {
            const int n = __shfl(nval, el);
            const int* ce = bucket + (size_t)(e0 + el) * CAP;
            f32x4 a0 = {0.f, 0.f, 0.f, 0.f};
            f32x4 a1 = a0, a2 = a0, a3 = a0, a4 = a0, a5 = a0, a6 = a0, a7 = a0;
            for (int j = 0; j < n; j += 16) {
#define GSLOT(k, acc)                                                        \
                {                                                            \
                    const int jj = j + 2 * (k) + rr;                         \
                    if (jj < n) {                                            \
                        const int idx = ce[jj];                              \
                        f32x4 v = *(const f32x4*)(xb + (size_t)idx * 512);   \
                        acc += v;                                            \
                    }                                                        \
                }
                GSLOT(0, a0) GSLOT(1, a1) GSLOT(2, a2) GSLOT(3, a3)
                GSLOT(4, a4) GSLOT(5, a5) GSLOT(6, a6) GSLOT(7, a7)
#undef GSLOT
            }
            f32x4 tot = ((a0 + a1) + (a2 + a3)) + ((a4 + a5) + (a6 + a7));
            tot[0] += __shfl_xor(tot[0], 32);
            tot[1] += __shfl_xor(tot[1], 32);
            tot[2] += __shfl_xor(tot[2], 32);
            tot[3] += __shfl_xor(tot[3], 32);
            const float scale = 1.0f / (float)(n > 0 ? n : 1);
            if (lane < 32) {
                unsigned int d0 = (unsigned)f2bf(tot[0] * scale) | ((unsigned)f2bf(tot[1] * scale) << 16);
                unsigned int d1 = (unsigned)f2bf(tot[2] * scale) | ((unsigned)f2bf(tot[3] * scale) << 16);
                *(uint2*)((char*)meanb + (size_t)(e0 + el) * 256 + c * 8) = make_uint2(d0, d1);
            }
        }
    }
}

// GEMM1: h = relu(meanb @ W1 + b1), blocked output h_blk[tile][ntp][32][32] bf16.
// 8 waves/block, W1^T fully LDS-resident (128 KB swizzled), 1 tile (32 rows)/wave.
__global__ __launch_bounds__(512) void gemm1_kernel(
    const unsigned short* __restrict__ meanb, const unsigned short* __restrict__ w1b,
    const float* __restrict__ b1, unsigned short* __restrict__ hblk, int reps)
{
    __shared__ unsigned short w1s[512 * 128];      // 128 KB: rows 256B, XOR-swizzled
    __shared__ unsigned short hsl[8][32 * HSP];    // 20 KB per-wave transpose buf

    const int tid  = threadIdx.x;
    const int lane = tid & 63;
    const int w    = tid >> 6;
    const int lrow = lane & 15;
    const int lgrp = lane >> 4;
    const int swz  = (lrow & 7) << 4;

    // stage w1b (bf16 [512][128]) -> LDS, swizzled
#pragma unroll
    for (int i = 0; i < 16; ++i) {
        const int o = i * 8192 + tid * 16;
        const int row = o >> 8, colb = o & 255;
        uint4 v = *(const uint4*)((const char*)w1b + o);
        *(uint4*)((char*)w1s + row * 256 + (colb ^ ((row & 7) << 4))) = v;
    }
    __syncthreads();

    const int tile = blockIdx.x * 8 + w;           // 0..4095
    const int rb   = tile * 32;
    unsigned short* hw = &hsl[w][0];

#pragma unroll 1
    for (int rep = 0; rep < reps; ++rep) {
        bf16x8 afrag[2][4];
#pragma unroll
        for (int mt = 0; mt < 2; ++mt)
#pragma unroll
            for (int kk = 0; kk < 4; ++kk)
                afrag[mt][kk] = *(const bf16x8*)(meanb +
                    (size_t)(rb + mt * 16 + lrow) * 128 + kk * 32 + lgrp * 8);

#pragma unroll 1
        for (int ntp = 0; ntp < 16; ++ntp) {
#pragma unroll
            for (int half = 0; half < 2; ++half) {
                const int nt = ntp * 2 + half;
                const float bias = b1[nt * 16 + lrow];
                f32x4 acc0 = {bias, bias, bias, bias};
                f32x4 acc1 = acc0;
#pragma unroll
                for (int kk = 0; kk < 4; ++kk) {
                    const bf16x8 bb = *(const bf16x8*)((const char*)w1s +
                        (nt * 16 + lrow) * 256 + ((kk * 64 + lgrp * 16) ^ swz));
                    acc0 = __builtin_amdgcn_mfma_f32_16x16x32_bf16(afrag[0][kk], bb, acc0, 0, 0, 0);
                    acc1 = __builtin_amdgcn_mfma_f32_16x16x32_bf16(afrag[1][kk], bb, acc1, 0, 0, 0);
                }
#pragma unroll
                for (int r = 0; r < 4; ++r) {
                    hw[(lgrp * 4 + r) * HSP + half * 16 + lrow]      = f2bf(fmaxf(acc0[r], 0.f));
                    hw[(16 + lgrp * 4 + r) * HSP + half * 16 + lrow] = f2bf(fmaxf(acc1[r], 0.f));
                }
            }
            // copy hsl (32x32, pitch HSP) -> h_blk contiguous 2 KB (two 1 KB wave-stores)
#pragma unroll
            for (int half = 0; half < 2; ++half) {
                const bf16x8 v = *(const bf16x8*)(hw +
                    (16 * half + (lane >> 2)) * HSP + (lane & 3) * 8);
                *(bf16x8*)(hblk + ((size_t)tile * 16 + ntp) * 1024 + half * 512 + lane * 8) = v;
            }
        }
    }
}

// GEMM2: out = h @ W2 + b2, reading blocked h_blk. 8 waves/block,
// W2^T fully LDS-resident (128 KB swizzled), 1 tile (32 rows)/wave, no inner barriers.
__global__ __launch_bounds__(512) void gemm2_kernel(
    const unsigned short* __restrict__ hblk, const unsigned short* __restrict__ w2b,
    const float* __restrict__ b2, float* __restrict__ out, int reps)
{
    __shared__ unsigned short w2s[128 * 512];      // 128 KB: rows 1024B, XOR-swizzled

    const int tid  = threadIdx.x;
    const int lane = tid & 63;
    const int w    = tid >> 6;
    const int lrow = lane & 15;
    const int lgrp = lane >> 4;
    const int swz  = (lrow & 7) << 4;

    // stage w2b (bf16 [128][512]) -> LDS, swizzled
#pragma unroll
    for (int i = 0; i < 16; ++i) {
        const int o = i * 8192 + tid * 16;
        const int row = o >> 10, colb = o & 1023;
        uint4 v = *(const uint4*)((const char*)w2b + o);
        *(uint4*)((char*)w2s + row * 1024 + (colb ^ ((row & 7) << 4))) = v;
    }
    __syncthreads();

    const int tile = blockIdx.x * 8 + w;           // 0..4095
    const int rb   = tile * 32;

    float bias2[8];
#pragma unroll
    for (int nt2 = 0; nt2 < 8; ++nt2) bias2[nt2] = b2[nt2 * 16 + lrow];

#pragma unroll 1
    for (int rep = 0; rep < reps; ++rep) {
        f32x4 acc2[2][8];
#pragma unroll
        for (int mt = 0; mt < 2; ++mt)
#pragma unroll
            for (int nt2 = 0; nt2 < 8; ++nt2) {
                f32x4 bv = {bias2[nt2], bias2[nt2], bias2[nt2], bias2[nt2]};
                acc2[mt][nt2] = bv;
            }

#pragma unroll 1
        for (int ks = 0; ks < 16; ++ks) {
            const bf16x8 a20 = *(const bf16x8*)(hblk +
                ((size_t)tile * 16 + ks) * 1024 + lrow * 32 + lgrp * 8);
            const bf16x8 a21 = *(const bf16x8*)(hblk +
                ((size_t)tile * 16 + ks) * 1024 + (16 + lrow) * 32 + lgrp * 8);
#pragma unroll
            for (int nt2 = 0; nt2 < 8; ++nt2) {
                const bf16x8 bb = *(const bf16x8*)((const char*)w2s +
                    (nt2 * 16 + lrow) * 1024 + ((ks * 64 + lgrp * 16) ^ swz));
                acc2[0][nt2] = __builtin_amdgcn_mfma_f32_16x16x32_bf16(a20, bb, acc2[0][nt2], 0, 0, 0);
                acc2[1][nt2] = __builtin_amdgcn_mfma_f32_16x16x32_bf16(a21, bb, acc2[1][nt2], 0, 0, 0);
            }
        }

#pragma unroll
        for (int mt = 0; mt < 2; ++mt)
#pragma unroll
            for (int nt2 = 0; nt2 < 8; ++nt2)
#pragma unroll
                for (int r = 0; r < 4; ++r)
                    out[(size_t)(rb + mt * 16 + lgrp * 4 + r) * 128 + nt2 * 16 + lrow] =
                        acc2[mt][nt2][r];
    }
}

extern "C" void kernel_launch(void* const* d_in, const int* in_sizes, int n_in,
                              void* d_out, int out_size, void* d_ws, size_t ws_size,
                              hipStream_t stream)
{
    const float* x  = (const float*)d_in[0];
    const int* hyper = (const int*)d_in[1];
    const float* W1 = (const float*)d_in[2];
    const float* b1 = (const float*)d_in[3];
    const float* W2 = (const float*)d_in[4];
    const float* b2 = (const float*)d_in[5];
    const int nnz = in_sizes[0] / D_IN;
    const int* seg = hyper + nnz;

    char* ws = (char*)d_ws;
    int* cur    = (int*)(ws + 0x0000000);            // E x 16 ints, 8 MB
    int* bucket = (int*)(ws + 0x0800000);            // E x CAP ints, 32 MB
    unsigned short* w1b = (unsigned short*)(ws + 0x2800000);   // 128 KB
    unsigned short* w2b = (unsigned short*)(ws + 0x2820000);   // 128 KB
    unsigned short* meanb = (unsigned short*)(ws + 0x2840000); // 32 MB
    unsigned short* hblk  = (unsigned short*)(ws + 0x4840000); // E x 512 bf16 = 128 MB
    float* out = (float*)d_out;

    // ---- real pipeline ----
    hipLaunchKernelGGL(zero16, dim3(2048), dim3(256), 0, stream, cur);
    hipLaunchKernelGGL(bucketfill_kernel, dim3(nnz / 1024), dim3(256), 0, stream,
                       seg, cur, bucket, nnz);
    hipLaunchKernelGGL(convw_kernel, dim3((D_IN * D_HID + D_HID * D_OUT) / 256), dim3(256), 0,
                       stream, W1, W2, w1b, w2b);
    hipLaunchKernelGGL(gather_kernel, dim3(E_EDGES / 64), dim3(256), 0, stream,
                       x, bucket, cur, meanb, 1);
    hipLaunchKernelGGL(gemm1_kernel, dim3(512), dim3(512), 0, stream,
                       meanb, w1b, b1, hblk, 1);
    hipLaunchKernelGGL(gemm2_kernel, dim3(512), dim3(512), 0, stream,
                       hblk, w2b, b2, out, 1);

    // ---- probes (idempotent re-runs; d_out ends identical) ----
    hipLaunchKernelGGL(gather_kernel, dim3(E_EDGES / 64), dim3(256), 0, stream,
                       x, bucket, cur, meanb, 4);
    hipLaunchKernelGGL(gemm1_kernel, dim3(512), dim3(512), 0, stream,
                       meanb, w1b, b1, hblk, 8);
    hipLaunchKernelGGL(gemm2_kernel, dim3(512), dim3(512), 0, stream,
                       hblk, w2b, b2, out, 8);
}